// Round 2
// baseline (160.141 us; speedup 1.0000x reference)
//
#include <hip/hip_runtime.h>

#define BB 2
#define NN 768
#define FF 128
#define HH 128
#define TS 32
#define ROWS 4
#define PAD 68
#define DELTA 0.02f
#define WCAP (1u << 20)

// k1: feats = relu(X@w1+b1)@w2+b2 (f64); Xc = X + gate*feats, stored f64 (authority) + f32 (fast pass).
// Block 0 additionally packs score-MLP weights (f64 + f32) and zeroes the worklist counter.
__global__ __launch_bounds__(128)
void edgefeat_kernel(const float* __restrict__ X,
                     const float* __restrict__ w1, const float* __restrict__ b1,
                     const float* __restrict__ w2, const float* __restrict__ b2,
                     const float* __restrict__ gatep,
                     const float* __restrict__ sm_w1, const float* __restrict__ sm_b1,
                     const float* __restrict__ sm_w2,
                     double* __restrict__ Xc64, float* __restrict__ Xc32,
                     double* __restrict__ wpack64, float* __restrict__ wpackf,
                     unsigned* __restrict__ counter) {
    __shared__ float  Xs[ROWS][FF];
    __shared__ double Hs[ROWS][HH + 2];
    const int h = threadIdx.x;            // 0..127
    const int row0 = blockIdx.x * ROWS;   // [0, B*N)

    if (blockIdx.x == 0) {
        double a  = (double)sm_w1[h];
        double bb = (double)sm_w1[HH + h];
        double be = (double)sm_b1[h];
        double wd = (double)sm_w2[2 * h + 1] - (double)sm_w2[2 * h];
        wpack64[4 * h + 0] = a;  wpack64[4 * h + 1] = bb;
        wpack64[4 * h + 2] = be; wpack64[4 * h + 3] = wd;
        wpackf[4 * h + 0] = (float)a;  wpackf[4 * h + 1] = (float)bb;
        wpackf[4 * h + 2] = (float)be; wpackf[4 * h + 3] = (float)wd;
        if (h == 0) *counter = 0u;
    }

    for (int r = 0; r < ROWS; ++r) Xs[r][h] = X[(size_t)(row0 + r) * FF + h];
    __syncthreads();

    double acc[ROWS];
    double bi = (double)b1[h];
    for (int r = 0; r < ROWS; ++r) acc[r] = bi;
#pragma unroll 4
    for (int f = 0; f < FF; ++f) {
        double w = (double)w1[f * HH + h];
        for (int r = 0; r < ROWS; ++r) acc[r] = fma((double)Xs[r][f], w, acc[r]);
    }
    for (int r = 0; r < ROWS; ++r) Hs[r][h] = acc[r] > 0.0 ? acc[r] : 0.0;
    __syncthreads();

    bi = (double)b2[h];
    for (int r = 0; r < ROWS; ++r) acc[r] = bi;
#pragma unroll 4
    for (int c = 0; c < HH; ++c) {
        double w = (double)w2[c * HH + h];
        for (int r = 0; r < ROWS; ++r) acc[r] = fma(Hs[r][c], w, acc[r]);
    }

    const double gate = (double)gatep[0];
    const int k = h & 1, d = h >> 1;
    const int b = row0 / NN;
    const int i0 = row0 % NN;
    for (int r = 0; r < ROWS; ++r) {
        double v = (double)Xs[r][h] + gate * acc[r];
        size_t idx = (((size_t)(b * 2 + k)) * NN + (i0 + r)) * 64 + d;
        Xc64[idx] = v;
        Xc32[idx] = (float)v;
    }
}

// k2: f32 fast pass over 32x32 tiles (ti<=tj). Near-zero margins -> worklist for f64 repair.
__global__ __launch_bounds__(256)
void decide32_kernel(const float* __restrict__ Xc32,
                     const float* __restrict__ wpackf,
                     const float* __restrict__ sm_b2,
                     const float* __restrict__ gumbel,
                     float* __restrict__ out,
                     unsigned* __restrict__ counter,
                     unsigned* __restrict__ worklist) {
    const int ti = blockIdx.x, tj = blockIdx.y, b = blockIdx.z;
    if (tj < ti) return;
    __shared__ float Ai[2][TS][PAD];
    __shared__ float Aj[2][TS][PAD];
    __shared__ float As[TS][36];
    const int tid = threadIdx.x;
    const int i0 = ti * TS, j0 = tj * TS;

    // stage f32 tiles: 1024 float4 units per matrix
    for (int q = 0; q < 4; ++q) {
        int flat = tid + 256 * q;
        int k  = flat >> 9;
        int r  = (flat >> 4) & 31;
        int d4 = (flat & 15) * 4;
        size_t base = ((size_t)(b * 2 + k)) * NN;
        float4 vi = *(const float4*)&Xc32[(base + i0 + r) * 64 + d4];
        *(float4*)&Ai[k][r][d4] = vi;
        float4 vj = *(const float4*)&Xc32[(base + j0 + r) * 64 + d4];
        *(float4*)&Aj[k][r][d4] = vj;
    }
    __syncthreads();

    const int rh = tid >> 4;          // 0..15
    const int ch = tid & 15;          // 0..15
    const int r0 = rh, r1 = rh + 16;
    const int c0 = ch, c1 = ch + 16;  // column split 16 apart -> 2-way LDS aliasing only (free)

    float p000 = 0.f, p001 = 0.f, p010 = 0.f, p011 = 0.f;
    float p100 = 0.f, p101 = 0.f, p110 = 0.f, p111 = 0.f;
#pragma unroll
    for (int d4 = 0; d4 < 64; d4 += 4) {
        float4 a00 = *(const float4*)&Ai[0][r0][d4];
        float4 a01 = *(const float4*)&Ai[0][r1][d4];
        float4 a10 = *(const float4*)&Ai[1][r0][d4];
        float4 a11 = *(const float4*)&Ai[1][r1][d4];
        float4 b00 = *(const float4*)&Aj[0][c0][d4];
        float4 b01 = *(const float4*)&Aj[0][c1][d4];
        float4 b10 = *(const float4*)&Aj[1][c0][d4];
        float4 b11 = *(const float4*)&Aj[1][c1][d4];
        p000 += a00.x*b00.x + a00.y*b00.y + a00.z*b00.z + a00.w*b00.w;
        p001 += a00.x*b01.x + a00.y*b01.y + a00.z*b01.z + a00.w*b01.w;
        p010 += a01.x*b00.x + a01.y*b00.y + a01.z*b00.z + a01.w*b00.w;
        p011 += a01.x*b01.x + a01.y*b01.y + a01.z*b01.z + a01.w*b01.w;
        p100 += a10.x*b10.x + a10.y*b10.y + a10.z*b10.z + a10.w*b10.w;
        p101 += a10.x*b11.x + a10.y*b11.y + a10.z*b11.z + a10.w*b11.w;
        p110 += a11.x*b10.x + a11.y*b10.y + a11.z*b10.z + a11.w*b10.w;
        p111 += a11.x*b11.x + a11.y*b11.y + a11.z*b11.z + a11.w*b11.w;
    }

    const float bd = sm_b2[1] - sm_b2[0];
    const float* gbase = &gumbel[(((size_t)b * NN) * NN) * 2];
    float2 g00 = *(const float2*)&gbase[(((size_t)(i0 + r0)) * NN + j0 + c0) * 2];
    float2 g01 = *(const float2*)&gbase[(((size_t)(i0 + r0)) * NN + j0 + c1) * 2];
    float2 g10 = *(const float2*)&gbase[(((size_t)(i0 + r1)) * NN + j0 + c0) * 2];
    float2 g11 = *(const float2*)&gbase[(((size_t)(i0 + r1)) * NN + j0 + c1) * 2];
    float m00 = bd + (g00.y - g00.x);
    float m01 = bd + (g01.y - g01.x);
    float m10 = bd + (g10.y - g10.x);
    float m11 = bd + (g11.y - g11.x);

#pragma unroll 8
    for (int c = 0; c < HH; ++c) {
        float4 w = *(const float4*)&wpackf[4 * c];  // {a, b, beta, wd}
        float t;
        t = fmaf(p100, w.y, fmaf(p000, w.x, w.z)); t = fmaxf(t, 0.f); m00 = fmaf(t, w.w, m00);
        t = fmaf(p101, w.y, fmaf(p001, w.x, w.z)); t = fmaxf(t, 0.f); m01 = fmaf(t, w.w, m01);
        t = fmaf(p110, w.y, fmaf(p010, w.x, w.z)); t = fmaxf(t, 0.f); m10 = fmaf(t, w.w, m10);
        t = fmaf(p111, w.y, fmaf(p011, w.x, w.z)); t = fmaxf(t, 0.f); m11 = fmaf(t, w.w, m11);
    }

    // flag near-threshold edges (upper triangle only) for exact f64 re-adjudication
    {
        int gi0 = i0 + r0, gi1 = i0 + r1, gj0 = j0 + c0, gj1 = j0 + c1;
        float mm[4] = {m00, m01, m10, m11};
        int ii[4] = {gi0, gi0, gi1, gi1};
        int jj[4] = {gj0, gj1, gj0, gj1};
        for (int e = 0; e < 4; ++e) {
            if (jj[e] > ii[e] && fabsf(mm[e]) < DELTA) {
                unsigned slot = atomicAdd(counter, 1u);
                if (slot < WCAP)
                    worklist[slot] = ((unsigned)(b * NN + ii[e])) * NN + (unsigned)jj[e];
            }
        }
    }

    As[r0][c0] = m00 > 0.f ? 1.f : 0.f;
    As[r0][c1] = m01 > 0.f ? 1.f : 0.f;
    As[r1][c0] = m10 > 0.f ? 1.f : 0.f;
    As[r1][c1] = m11 > 0.f ? 1.f : 0.f;
    __syncthreads();

    // coalesced float4 stores from As
    const int r  = tid >> 3;          // 0..31
    const int c4 = (tid & 7) * 4;     // 0..28
    if (ti == tj) {
        float4 v;
        float* vp = (float*)&v;
        for (int u = 0; u < 4; ++u) {
            int c = c4 + u;
            vp[u] = (r < c) ? As[r][c] : ((r > c) ? As[c][r] : 0.f);
        }
        *(float4*)&out[((size_t)b * NN + i0 + r) * NN + j0 + c4] = v;
    } else {
        float4 v = *(const float4*)&As[r][c4];
        *(float4*)&out[((size_t)b * NN + i0 + r) * NN + j0 + c4] = v;
        float4 t;
        float* tp = (float*)&t;
        for (int u = 0; u < 4; ++u) tp[u] = As[c4 + u][r];
        *(float4*)&out[((size_t)b * NN + j0 + r) * NN + i0 + c4] = t;
    }
}

// k3: exact f64 re-adjudication of flagged edges
__global__ __launch_bounds__(64)
void repair_kernel(const double* __restrict__ Xc64,
                   const double* __restrict__ wpack64,
                   const float* __restrict__ sm_b2,
                   const float* __restrict__ gumbel,
                   float* __restrict__ out,
                   const unsigned* __restrict__ counter,
                   const unsigned* __restrict__ worklist) {
    unsigned n = *counter;
    if (n > WCAP) n = WCAP;
    for (unsigned t = blockIdx.x * blockDim.x + threadIdx.x; t < n;
         t += gridDim.x * blockDim.x) {
        unsigned e = worklist[t];
        int j = e % NN;
        unsigned rr = e / NN;
        int i = rr % NN;
        int b = rr / NN;
        const double* xi0 = &Xc64[(((size_t)(b * 2 + 0)) * NN + i) * 64];
        const double* xj0 = &Xc64[(((size_t)(b * 2 + 0)) * NN + j) * 64];
        const double* xi1 = &Xc64[(((size_t)(b * 2 + 1)) * NN + i) * 64];
        const double* xj1 = &Xc64[(((size_t)(b * 2 + 1)) * NN + j) * 64];
        double p0a = 0, p0b = 0, p1a = 0, p1b = 0;
        for (int d = 0; d < 64; d += 2) {
            p0a = fma(xi0[d],     xj0[d],     p0a);
            p0b = fma(xi0[d + 1], xj0[d + 1], p0b);
            p1a = fma(xi1[d],     xj1[d],     p1a);
            p1b = fma(xi1[d + 1], xj1[d + 1], p1b);
        }
        double p0 = p0a + p0b, p1 = p1a + p1b;
        const float* g = &gumbel[(((size_t)b * NN + i) * NN + j) * 2];
        double m = ((double)sm_b2[1] - (double)sm_b2[0]) + ((double)g[1] - (double)g[0]);
        for (int c = 0; c < HH; ++c) {
            double2 wab = *(const double2*)&wpack64[4 * c];
            double2 wbw = *(const double2*)&wpack64[4 * c + 2];
            double tt = fma(p1, wab.y, fma(p0, wab.x, wbw.x));
            tt = fmax(tt, 0.0);
            m = fma(tt, wbw.y, m);
        }
        float v = m > 0.0 ? 1.f : 0.f;
        out[((size_t)b * NN + i) * NN + j] = v;
        out[((size_t)b * NN + j) * NN + i] = v;
    }
}

extern "C" void kernel_launch(void* const* d_in, const int* in_sizes, int n_in,
                              void* d_out, int out_size, void* d_ws, size_t ws_size,
                              hipStream_t stream) {
    const float* X      = (const float*)d_in[0];
    const float* ef_w1  = (const float*)d_in[1];
    const float* ef_b1  = (const float*)d_in[2];
    const float* ef_w2  = (const float*)d_in[3];
    const float* ef_b2  = (const float*)d_in[4];
    const float* gate   = (const float*)d_in[5];
    const float* sm_w1  = (const float*)d_in[6];
    const float* sm_b1  = (const float*)d_in[7];
    const float* sm_w2  = (const float*)d_in[8];
    const float* sm_b2  = (const float*)d_in[9];
    const float* gumbel = (const float*)d_in[10];
    float* out = (float*)d_out;

    double*   Xc64     = (double*)d_ws;                     // 2*2*768*64 = 196608 doubles
    float*    Xc32     = (float*)(Xc64 + 196608);           // 196608 floats
    double*   wpack64  = (double*)(Xc32 + 196608);          // 512 doubles
    float*    wpackf   = (float*)(wpack64 + 512);           // 512 floats
    unsigned* counter  = (unsigned*)(wpackf + 512);         // 1 (+pad to 16B)
    unsigned* worklist = counter + 4;                       // WCAP entries

    edgefeat_kernel<<<BB * NN / ROWS, 128, 0, stream>>>(
        X, ef_w1, ef_b1, ef_w2, ef_b2, gate, sm_w1, sm_b1, sm_w2,
        Xc64, Xc32, wpack64, wpackf, counter);
    dim3 grid(NN / TS, NN / TS, BB);
    decide32_kernel<<<grid, 256, 0, stream>>>(Xc32, wpackf, sm_b2, gumbel, out,
                                              counter, worklist);
    repair_kernel<<<32, 64, 0, stream>>>(Xc64, wpack64, sm_b2, gumbel, out,
                                         counter, worklist);
}

// Round 3
// 149.205 us; speedup vs baseline: 1.0733x; 1.0733x over previous
//
#include <hip/hip_runtime.h>

#define BB 2
#define NN 768
#define FF 128
#define HH 128
#define TS 32
#define PAD 68
#define DELTA 0.02f
#define WCAP (1u << 20)

// k1: fused 2-layer edge-feat MLP in f64, 2 rows/block, thread=(row,col).
// Xc = X + gate*feats stored f64 (authority) + f32 (fast pass).
// Block 0 also packs score-MLP weights and zeroes the worklist counter.
__global__ __launch_bounds__(256)
void edgefeat_kernel(const float* __restrict__ X,
                     const float* __restrict__ w1, const float* __restrict__ b1,
                     const float* __restrict__ w2, const float* __restrict__ b2,
                     const float* __restrict__ gatep,
                     const float* __restrict__ sm_w1, const float* __restrict__ sm_b1,
                     const float* __restrict__ sm_w2,
                     double* __restrict__ Xc64, float* __restrict__ Xc32,
                     double* __restrict__ wpack64, float* __restrict__ wpackf,
                     unsigned* __restrict__ counter) {
    __shared__ float  Xs[2][FF];
    __shared__ double Hs[2][HH + 2];
    const int tid = threadIdx.x;
    const int r = tid >> 7;        // 0..1
    const int c = tid & 127;       // 0..127
    const int row0 = blockIdx.x * 2;

    if (blockIdx.x == 0 && r == 0) {
        double a  = (double)sm_w1[c];
        double bb = (double)sm_w1[HH + c];
        double be = (double)sm_b1[c];
        double wd = (double)sm_w2[2 * c + 1] - (double)sm_w2[2 * c];
        wpack64[4 * c + 0] = a;  wpack64[4 * c + 1] = bb;
        wpack64[4 * c + 2] = be; wpack64[4 * c + 3] = wd;
        wpackf[4 * c + 0] = (float)a;  wpackf[4 * c + 1] = (float)bb;
        wpackf[4 * c + 2] = (float)be; wpackf[4 * c + 3] = (float)wd;
        if (c == 0) *counter = 0u;
    }

    Xs[r][c] = X[(size_t)(row0 + r) * FF + c];
    __syncthreads();

    // layer 1: two independent chains over halves of f
    double acc0 = (double)b1[c], acc1 = 0.0;
#pragma unroll 8
    for (int f = 0; f < 64; ++f) {
        acc0 = fma((double)Xs[r][f],      (double)w1[f * HH + c],        acc0);
        acc1 = fma((double)Xs[r][f + 64], (double)w1[(f + 64) * HH + c], acc1);
    }
    double h1 = acc0 + acc1;
    Hs[r][c] = h1 > 0.0 ? h1 : 0.0;
    __syncthreads();

    // layer 2
    acc0 = (double)b2[c]; acc1 = 0.0;
#pragma unroll 8
    for (int f = 0; f < 64; ++f) {
        acc0 = fma(Hs[r][f],      (double)w2[f * HH + c],        acc0);
        acc1 = fma(Hs[r][f + 64], (double)w2[(f + 64) * HH + c], acc1);
    }

    const double gate = (double)gatep[0];
    double v = (double)Xs[r][c] + gate * (acc0 + acc1);
    const int g = row0 + r;
    const int b = g / NN, i = g % NN;
    const int k = c & 1, d = c >> 1;
    size_t idx = (((size_t)(b * 2 + k)) * NN + i) * 64 + d;
    Xc64[idx] = v;
    Xc32[idx] = (float)v;
}

// k2: f32 fast pass, 32x32 tiles (ti<=tj), 512 threads, 2 edges/thread.
__global__ __launch_bounds__(512)
void decide32_kernel(const float* __restrict__ Xc32,
                     const float* __restrict__ wpackf,
                     const float* __restrict__ sm_b2,
                     const float* __restrict__ gumbel,
                     float* __restrict__ out,
                     unsigned* __restrict__ counter,
                     unsigned* __restrict__ worklist) {
    const int ti = blockIdx.x, tj = blockIdx.y, b = blockIdx.z;
    if (tj < ti) return;
    __shared__ float Ai[2][TS][PAD];
    __shared__ float Aj[2][TS][PAD];
    __shared__ float As[TS][36];
    const int tid = threadIdx.x;
    const int i0 = ti * TS, j0 = tj * TS;

    for (int q = 0; q < 2; ++q) {
        int flat = tid + 512 * q;        // [0,1024)
        int k  = flat >> 9;
        int rr = (flat >> 4) & 31;
        int d4 = (flat & 15) * 4;
        size_t base = ((size_t)(b * 2 + k)) * NN;
        *(float4*)&Ai[k][rr][d4] = *(const float4*)&Xc32[(base + i0 + rr) * 64 + d4];
        *(float4*)&Aj[k][rr][d4] = *(const float4*)&Xc32[(base + j0 + rr) * 64 + d4];
    }
    __syncthreads();

    const int rh = tid >> 4;          // 0..31 (row)
    const int ch = tid & 15;
    const int c0 = ch, c1 = ch + 16;  // 2 edges per thread

    float p00 = 0.f, p01 = 0.f, p10 = 0.f, p11 = 0.f;  // p[k][edge]
#pragma unroll
    for (int d4 = 0; d4 < 64; d4 += 4) {
        float4 a0  = *(const float4*)&Ai[0][rh][d4];
        float4 a1  = *(const float4*)&Ai[1][rh][d4];
        float4 q00 = *(const float4*)&Aj[0][c0][d4];
        float4 q01 = *(const float4*)&Aj[0][c1][d4];
        float4 q10 = *(const float4*)&Aj[1][c0][d4];
        float4 q11 = *(const float4*)&Aj[1][c1][d4];
        p00 += a0.x*q00.x + a0.y*q00.y + a0.z*q00.z + a0.w*q00.w;
        p01 += a0.x*q01.x + a0.y*q01.y + a0.z*q01.z + a0.w*q01.w;
        p10 += a1.x*q10.x + a1.y*q10.y + a1.z*q10.z + a1.w*q10.w;
        p11 += a1.x*q11.x + a1.y*q11.y + a1.z*q11.z + a1.w*q11.w;
    }

    const float bd = sm_b2[1] - sm_b2[0];
    const float* gbase = &gumbel[(((size_t)b * NN) * NN) * 2];
    float2 g0 = *(const float2*)&gbase[(((size_t)(i0 + rh)) * NN + j0 + c0) * 2];
    float2 g1 = *(const float2*)&gbase[(((size_t)(i0 + rh)) * NN + j0 + c1) * 2];
    float ma0 = bd + (g0.y - g0.x), mb0 = 0.f;   // edge c0: two chains
    float ma1 = bd + (g1.y - g1.x), mb1 = 0.f;   // edge c1

#pragma unroll 4
    for (int cc = 0; cc < HH; cc += 2) {
        float4 w0 = *(const float4*)&wpackf[4 * cc];      // {a,b,beta,wd}
        float4 w1v = *(const float4*)&wpackf[4 * cc + 4];
        float t;
        t = fmaf(p10, w0.y,  fmaf(p00, w0.x,  w0.z));  t = fmaxf(t, 0.f); ma0 = fmaf(t, w0.w,  ma0);
        t = fmaf(p11, w0.y,  fmaf(p01, w0.x,  w0.z));  t = fmaxf(t, 0.f); ma1 = fmaf(t, w0.w,  ma1);
        t = fmaf(p10, w1v.y, fmaf(p00, w1v.x, w1v.z)); t = fmaxf(t, 0.f); mb0 = fmaf(t, w1v.w, mb0);
        t = fmaf(p11, w1v.y, fmaf(p01, w1v.x, w1v.z)); t = fmaxf(t, 0.f); mb1 = fmaf(t, w1v.w, mb1);
    }
    float m0 = ma0 + mb0;
    float m1 = ma1 + mb1;

    // flag near-threshold upper-triangle edges for f64 repair
    {
        int gi = i0 + rh;
        int jj[2] = {j0 + c0, j0 + c1};
        float mm[2] = {m0, m1};
        for (int e = 0; e < 2; ++e) {
            if (jj[e] > gi && fabsf(mm[e]) < DELTA) {
                unsigned slot = atomicAdd(counter, 1u);
                if (slot < WCAP)
                    worklist[slot] = ((unsigned)(b * NN + gi)) * NN + (unsigned)jj[e];
            }
        }
    }

    As[rh][c0] = m0 > 0.f ? 1.f : 0.f;
    As[rh][c1] = m1 > 0.f ? 1.f : 0.f;
    __syncthreads();

    if (tid < 256) {
        const int r  = tid >> 3;
        const int c4 = (tid & 7) * 4;
        if (ti == tj) {
            float4 v; float* vp = (float*)&v;
            for (int u = 0; u < 4; ++u) {
                int c = c4 + u;
                vp[u] = (r < c) ? As[r][c] : ((r > c) ? As[c][r] : 0.f);
            }
            *(float4*)&out[((size_t)b * NN + i0 + r) * NN + j0 + c4] = v;
        } else {
            float4 v = *(const float4*)&As[r][c4];
            *(float4*)&out[((size_t)b * NN + i0 + r) * NN + j0 + c4] = v;
            float4 t; float* tp = (float*)&t;
            for (int u = 0; u < 4; ++u) tp[u] = As[c4 + u][r];
            *(float4*)&out[((size_t)b * NN + j0 + r) * NN + i0 + c4] = t;
        }
    }
}

// k3: exact f64 re-adjudication of flagged edges
__global__ __launch_bounds__(64)
void repair_kernel(const double* __restrict__ Xc64,
                   const double* __restrict__ wpack64,
                   const float* __restrict__ sm_b2,
                   const float* __restrict__ gumbel,
                   float* __restrict__ out,
                   const unsigned* __restrict__ counter,
                   const unsigned* __restrict__ worklist) {
    unsigned n = *counter;
    if (n > WCAP) n = WCAP;
    for (unsigned t = blockIdx.x * blockDim.x + threadIdx.x; t < n;
         t += gridDim.x * blockDim.x) {
        unsigned e = worklist[t];
        int j = e % NN;
        unsigned rr = e / NN;
        int i = rr % NN;
        int b = rr / NN;
        const double* xi0 = &Xc64[(((size_t)(b * 2 + 0)) * NN + i) * 64];
        const double* xj0 = &Xc64[(((size_t)(b * 2 + 0)) * NN + j) * 64];
        const double* xi1 = &Xc64[(((size_t)(b * 2 + 1)) * NN + i) * 64];
        const double* xj1 = &Xc64[(((size_t)(b * 2 + 1)) * NN + j) * 64];
        double p0a = 0, p0b = 0, p1a = 0, p1b = 0;
        for (int d = 0; d < 64; d += 2) {
            p0a = fma(xi0[d],     xj0[d],     p0a);
            p0b = fma(xi0[d + 1], xj0[d + 1], p0b);
            p1a = fma(xi1[d],     xj1[d],     p1a);
            p1b = fma(xi1[d + 1], xj1[d + 1], p1b);
        }
        double p0 = p0a + p0b, p1 = p1a + p1b;
        const float* g = &gumbel[(((size_t)b * NN + i) * NN + j) * 2];
        double mA = ((double)sm_b2[1] - (double)sm_b2[0]) + ((double)g[1] - (double)g[0]);
        double mB = 0.0;
        for (int c = 0; c < HH; c += 2) {
            double2 wab0 = *(const double2*)&wpack64[4 * c];
            double2 wbw0 = *(const double2*)&wpack64[4 * c + 2];
            double2 wab1 = *(const double2*)&wpack64[4 * c + 4];
            double2 wbw1 = *(const double2*)&wpack64[4 * c + 6];
            double t0 = fma(p1, wab0.y, fma(p0, wab0.x, wbw0.x));
            double t1 = fma(p1, wab1.y, fma(p0, wab1.x, wbw1.x));
            t0 = fmax(t0, 0.0); t1 = fmax(t1, 0.0);
            mA = fma(t0, wbw0.y, mA);
            mB = fma(t1, wbw1.y, mB);
        }
        float v = (mA + mB) > 0.0 ? 1.f : 0.f;
        out[((size_t)b * NN + i) * NN + j] = v;
        out[((size_t)b * NN + j) * NN + i] = v;
    }
}

extern "C" void kernel_launch(void* const* d_in, const int* in_sizes, int n_in,
                              void* d_out, int out_size, void* d_ws, size_t ws_size,
                              hipStream_t stream) {
    const float* X      = (const float*)d_in[0];
    const float* ef_w1  = (const float*)d_in[1];
    const float* ef_b1  = (const float*)d_in[2];
    const float* ef_w2  = (const float*)d_in[3];
    const float* ef_b2  = (const float*)d_in[4];
    const float* gate   = (const float*)d_in[5];
    const float* sm_w1  = (const float*)d_in[6];
    const float* sm_b1  = (const float*)d_in[7];
    const float* sm_w2  = (const float*)d_in[8];
    const float* sm_b2  = (const float*)d_in[9];
    const float* gumbel = (const float*)d_in[10];
    float* out = (float*)d_out;

    double*   Xc64     = (double*)d_ws;                     // 196608 doubles
    float*    Xc32     = (float*)(Xc64 + 196608);           // 196608 floats
    double*   wpack64  = (double*)(Xc32 + 196608);          // 512 doubles
    float*    wpackf   = (float*)(wpack64 + 512);           // 512 floats
    unsigned* counter  = (unsigned*)(wpackf + 512);
    unsigned* worklist = counter + 4;                       // WCAP entries

    edgefeat_kernel<<<BB * NN / 2, 256, 0, stream>>>(
        X, ef_w1, ef_b1, ef_w2, ef_b2, gate, sm_w1, sm_b1, sm_w2,
        Xc64, Xc32, wpack64, wpackf, counter);
    dim3 grid(NN / TS, NN / TS, BB);
    decide32_kernel<<<grid, 512, 0, stream>>>(Xc32, wpackf, sm_b2, gumbel, out,
                                              counter, worklist);
    repair_kernel<<<64, 64, 0, stream>>>(Xc64, wpack64, sm_b2, gumbel, out,
                                         counter, worklist);
}

// Round 4
// 147.793 us; speedup vs baseline: 1.0835x; 1.0096x over previous
//
#include <hip/hip_runtime.h>

#define BB 2
#define NN 768
#define FF 128
#define HH 128
#define TS 32
#define MT (NN / TS)          // 24 tiles per dim
#define NTILE (MT * (MT + 1) / 2)  // 300 upper tiles
#define PAD 68
#define DELTA 0.02f
#define WCAP (1u << 20)

// k1: fused 2-layer edge-feat MLP in f64, 2 rows/block, thread=(row,col).
// Xc = X + gate*feats stored f64 (authority) + f32 (fast pass).
// Block 0 also packs score-MLP weights and zeroes the worklist counter.
__global__ __launch_bounds__(256)
void edgefeat_kernel(const float* __restrict__ X,
                     const float* __restrict__ w1, const float* __restrict__ b1,
                     const float* __restrict__ w2, const float* __restrict__ b2,
                     const float* __restrict__ gatep,
                     const float* __restrict__ sm_w1, const float* __restrict__ sm_b1,
                     const float* __restrict__ sm_w2,
                     double* __restrict__ Xc64, float* __restrict__ Xc32,
                     double* __restrict__ wpack64, float* __restrict__ wpackf,
                     unsigned* __restrict__ counter) {
    __shared__ float  Xs[2][FF];
    __shared__ double Hs[2][HH + 2];
    const int tid = threadIdx.x;
    const int r = tid >> 7;        // 0..1
    const int c = tid & 127;       // 0..127
    const int row0 = blockIdx.x * 2;

    if (blockIdx.x == 0 && r == 0) {
        double a  = (double)sm_w1[c];
        double bb = (double)sm_w1[HH + c];
        double be = (double)sm_b1[c];
        double wd = (double)sm_w2[2 * c + 1] - (double)sm_w2[2 * c];
        wpack64[4 * c + 0] = a;  wpack64[4 * c + 1] = bb;
        wpack64[4 * c + 2] = be; wpack64[4 * c + 3] = wd;
        wpackf[4 * c + 0] = (float)a;  wpackf[4 * c + 1] = (float)bb;
        wpackf[4 * c + 2] = (float)be; wpackf[4 * c + 3] = (float)wd;
        if (c == 0) *counter = 0u;
    }

    Xs[r][c] = X[(size_t)(row0 + r) * FF + c];
    __syncthreads();

    double acc0 = (double)b1[c], acc1 = 0.0;
#pragma unroll 8
    for (int f = 0; f < 64; ++f) {
        acc0 = fma((double)Xs[r][f],      (double)w1[f * HH + c],        acc0);
        acc1 = fma((double)Xs[r][f + 64], (double)w1[(f + 64) * HH + c], acc1);
    }
    double h1 = acc0 + acc1;
    Hs[r][c] = h1 > 0.0 ? h1 : 0.0;
    __syncthreads();

    acc0 = (double)b2[c]; acc1 = 0.0;
#pragma unroll 8
    for (int f = 0; f < 64; ++f) {
        acc0 = fma(Hs[r][f],      (double)w2[f * HH + c],        acc0);
        acc1 = fma(Hs[r][f + 64], (double)w2[(f + 64) * HH + c], acc1);
    }

    const double gate = (double)gatep[0];
    double v = (double)Xs[r][c] + gate * (acc0 + acc1);
    const int g = row0 + r;
    const int b = g / NN, i = g % NN;
    const int k = c & 1, d = c >> 1;
    size_t idx = (((size_t)(b * 2 + k)) * NN + i) * 64 + d;
    Xc64[idx] = v;
    Xc32[idx] = (float)v;
}

// k2: f32 fast pass. Upper tiles only (300 per batch). Weights staged in LDS
// (DS is in-order -> fine-grained lgkmcnt, no SMEM lgkmcnt(0) drains).
__global__ __launch_bounds__(512)
void decide32_kernel(const float* __restrict__ Xc32,
                     const float* __restrict__ wpackf,
                     const float* __restrict__ sm_b2,
                     const float* __restrict__ gumbel,
                     float* __restrict__ out,
                     unsigned* __restrict__ counter,
                     unsigned* __restrict__ worklist) {
    // decode flat upper-tile index -> (ti, tj), uniform scalar loop
    int off = blockIdx.x;
    int ti = 0;
    while (off >= MT - ti) { off -= MT - ti; ++ti; }
    const int tj = ti + off;
    const int b = blockIdx.y;

    __shared__ float Ai[2][TS][PAD];
    __shared__ float Aj[2][TS][PAD];
    __shared__ float sW[HH * 4];
    __shared__ float As[TS][36];
    const int tid = threadIdx.x;
    const int i0 = ti * TS, j0 = tj * TS;

    // stage Xc tiles + weight table
    for (int q = 0; q < 2; ++q) {
        int flat = tid + 512 * q;        // [0,1024)
        int k  = flat >> 9;
        int rr = (flat >> 4) & 31;
        int d4 = (flat & 15) * 4;
        size_t base = ((size_t)(b * 2 + k)) * NN;
        *(float4*)&Ai[k][rr][d4] = *(const float4*)&Xc32[(base + i0 + rr) * 64 + d4];
        *(float4*)&Aj[k][rr][d4] = *(const float4*)&Xc32[(base + j0 + rr) * 64 + d4];
    }
    sW[tid] = wpackf[tid];
    __syncthreads();

    const int rh = tid >> 4;          // 0..31 (row)
    const int ch = tid & 15;
    const int c0 = ch, c1 = ch + 16;  // 2 edges per thread

    // gumbel loads issued early (HBM latency overlaps gram)
    const float bd = sm_b2[1] - sm_b2[0];
    const float* gbase = &gumbel[(((size_t)b * NN) * NN) * 2];
    float2 g0 = *(const float2*)&gbase[(((size_t)(i0 + rh)) * NN + j0 + c0) * 2];
    float2 g1 = *(const float2*)&gbase[(((size_t)(i0 + rh)) * NN + j0 + c1) * 2];

    float p00 = 0.f, p01 = 0.f, p10 = 0.f, p11 = 0.f;  // p[k][edge]
#pragma unroll
    for (int d4 = 0; d4 < 64; d4 += 4) {
        float4 a0  = *(const float4*)&Ai[0][rh][d4];
        float4 a1  = *(const float4*)&Ai[1][rh][d4];
        float4 q00 = *(const float4*)&Aj[0][c0][d4];
        float4 q01 = *(const float4*)&Aj[0][c1][d4];
        float4 q10 = *(const float4*)&Aj[1][c0][d4];
        float4 q11 = *(const float4*)&Aj[1][c1][d4];
        p00 += a0.x*q00.x + a0.y*q00.y + a0.z*q00.z + a0.w*q00.w;
        p01 += a0.x*q01.x + a0.y*q01.y + a0.z*q01.z + a0.w*q01.w;
        p10 += a1.x*q10.x + a1.y*q10.y + a1.z*q10.z + a1.w*q10.w;
        p11 += a1.x*q11.x + a1.y*q11.y + a1.z*q11.z + a1.w*q11.w;
    }

    float ma0 = bd + (g0.y - g0.x), mb0 = 0.f;   // edge c0: two chains
    float ma1 = bd + (g1.y - g1.x), mb1 = 0.f;   // edge c1

#pragma unroll 8
    for (int cc = 0; cc < HH; cc += 2) {
        float4 w0  = *(const float4*)&sW[4 * cc];      // {a,b,beta,wd} — LDS broadcast
        float4 w1v = *(const float4*)&sW[4 * cc + 4];
        float t;
        t = fmaf(p10, w0.y,  fmaf(p00, w0.x,  w0.z));  t = fmaxf(t, 0.f); ma0 = fmaf(t, w0.w,  ma0);
        t = fmaf(p11, w0.y,  fmaf(p01, w0.x,  w0.z));  t = fmaxf(t, 0.f); ma1 = fmaf(t, w0.w,  ma1);
        t = fmaf(p10, w1v.y, fmaf(p00, w1v.x, w1v.z)); t = fmaxf(t, 0.f); mb0 = fmaf(t, w1v.w, mb0);
        t = fmaf(p11, w1v.y, fmaf(p01, w1v.x, w1v.z)); t = fmaxf(t, 0.f); mb1 = fmaf(t, w1v.w, mb1);
    }
    float m0 = ma0 + mb0;
    float m1 = ma1 + mb1;

    // flag near-threshold upper-triangle edges for f64 repair
    {
        int gi = i0 + rh;
        int jj[2] = {j0 + c0, j0 + c1};
        float mm[2] = {m0, m1};
        for (int e = 0; e < 2; ++e) {
            if (jj[e] > gi && fabsf(mm[e]) < DELTA) {
                unsigned slot = atomicAdd(counter, 1u);
                if (slot < WCAP)
                    worklist[slot] = ((unsigned)(b * NN + gi)) * NN + (unsigned)jj[e];
            }
        }
    }

    As[rh][c0] = m0 > 0.f ? 1.f : 0.f;
    As[rh][c1] = m1 > 0.f ? 1.f : 0.f;
    __syncthreads();

    if (tid < 256) {
        const int r  = tid >> 3;
        const int c4 = (tid & 7) * 4;
        if (ti == tj) {
            float4 v; float* vp = (float*)&v;
            for (int u = 0; u < 4; ++u) {
                int c = c4 + u;
                vp[u] = (r < c) ? As[r][c] : ((r > c) ? As[c][r] : 0.f);
            }
            *(float4*)&out[((size_t)b * NN + i0 + r) * NN + j0 + c4] = v;
        } else {
            float4 v = *(const float4*)&As[r][c4];
            *(float4*)&out[((size_t)b * NN + i0 + r) * NN + j0 + c4] = v;
            float4 t; float* tp = (float*)&t;
            for (int u = 0; u < 4; ++u) tp[u] = As[c4 + u][r];
            *(float4*)&out[((size_t)b * NN + j0 + r) * NN + i0 + c4] = t;
        }
    }
}

// k3: exact f64 re-adjudication of flagged edges
__global__ __launch_bounds__(64)
void repair_kernel(const double* __restrict__ Xc64,
                   const double* __restrict__ wpack64,
                   const float* __restrict__ sm_b2,
                   const float* __restrict__ gumbel,
                   float* __restrict__ out,
                   const unsigned* __restrict__ counter,
                   const unsigned* __restrict__ worklist) {
    unsigned n = *counter;
    if (n > WCAP) n = WCAP;
    for (unsigned t = blockIdx.x * blockDim.x + threadIdx.x; t < n;
         t += gridDim.x * blockDim.x) {
        unsigned e = worklist[t];
        int j = e % NN;
        unsigned rr = e / NN;
        int i = rr % NN;
        int b = rr / NN;
        const double* xi0 = &Xc64[(((size_t)(b * 2 + 0)) * NN + i) * 64];
        const double* xj0 = &Xc64[(((size_t)(b * 2 + 0)) * NN + j) * 64];
        const double* xi1 = &Xc64[(((size_t)(b * 2 + 1)) * NN + i) * 64];
        const double* xj1 = &Xc64[(((size_t)(b * 2 + 1)) * NN + j) * 64];
        double p0a = 0, p0b = 0, p1a = 0, p1b = 0;
        for (int d = 0; d < 64; d += 2) {
            p0a = fma(xi0[d],     xj0[d],     p0a);
            p0b = fma(xi0[d + 1], xj0[d + 1], p0b);
            p1a = fma(xi1[d],     xj1[d],     p1a);
            p1b = fma(xi1[d + 1], xj1[d + 1], p1b);
        }
        double p0 = p0a + p0b, p1 = p1a + p1b;
        const float* g = &gumbel[(((size_t)b * NN + i) * NN + j) * 2];
        double mA = ((double)sm_b2[1] - (double)sm_b2[0]) + ((double)g[1] - (double)g[0]);
        double mB = 0.0;
        for (int c = 0; c < HH; c += 2) {
            double2 wab0 = *(const double2*)&wpack64[4 * c];
            double2 wbw0 = *(const double2*)&wpack64[4 * c + 2];
            double2 wab1 = *(const double2*)&wpack64[4 * c + 4];
            double2 wbw1 = *(const double2*)&wpack64[4 * c + 6];
            double t0 = fma(p1, wab0.y, fma(p0, wab0.x, wbw0.x));
            double t1 = fma(p1, wab1.y, fma(p0, wab1.x, wbw1.x));
            t0 = fmax(t0, 0.0); t1 = fmax(t1, 0.0);
            mA = fma(t0, wbw0.y, mA);
            mB = fma(t1, wbw1.y, mB);
        }
        float v = (mA + mB) > 0.0 ? 1.f : 0.f;
        out[((size_t)b * NN + i) * NN + j] = v;
        out[((size_t)b * NN + j) * NN + i] = v;
    }
}

extern "C" void kernel_launch(void* const* d_in, const int* in_sizes, int n_in,
                              void* d_out, int out_size, void* d_ws, size_t ws_size,
                              hipStream_t stream) {
    const float* X      = (const float*)d_in[0];
    const float* ef_w1  = (const float*)d_in[1];
    const float* ef_b1  = (const float*)d_in[2];
    const float* ef_w2  = (const float*)d_in[3];
    const float* ef_b2  = (const float*)d_in[4];
    const float* gate   = (const float*)d_in[5];
    const float* sm_w1  = (const float*)d_in[6];
    const float* sm_b1  = (const float*)d_in[7];
    const float* sm_w2  = (const float*)d_in[8];
    const float* sm_b2  = (const float*)d_in[9];
    const float* gumbel = (const float*)d_in[10];
    float* out = (float*)d_out;

    double*   Xc64     = (double*)d_ws;                     // 196608 doubles
    float*    Xc32     = (float*)(Xc64 + 196608);           // 196608 floats
    double*   wpack64  = (double*)(Xc32 + 196608);          // 512 doubles
    float*    wpackf   = (float*)(wpack64 + 512);           // 512 floats
    unsigned* counter  = (unsigned*)(wpackf + 512);
    unsigned* worklist = counter + 4;                       // WCAP entries

    edgefeat_kernel<<<BB * NN / 2, 256, 0, stream>>>(
        X, ef_w1, ef_b1, ef_w2, ef_b2, gate, sm_w1, sm_b1, sm_w2,
        Xc64, Xc32, wpack64, wpackf, counter);
    dim3 grid(NTILE, BB);
    decide32_kernel<<<grid, 512, 0, stream>>>(Xc32, wpackf, sm_b2, gumbel, out,
                                              counter, worklist);
    repair_kernel<<<64, 64, 0, stream>>>(Xc64, wpack64, sm_b2, gumbel, out,
                                         counter, worklist);
}